// Round 1
// baseline (174.838 us; speedup 1.0000x reference)
//
#include <hip/hip_runtime.h>
#include <math.h>

#define T1 17
#define NN 2048
#define DIN 9
#define CC 8
#define KK 5
#define RR 8              // waves per block = donor chunks
#define CHUNK (NN / RR)   // 256 donors per wave

__device__ __forceinline__ bool lexlt(float d1, int j1, float d2, int j2) {
  return d1 < d2 || (d1 == d2 && j1 < j2);
}

// Build 17-bit presence bitmask per row: bit t set iff mask[t][i]==0.
__global__ void prep_kernel(const int* __restrict__ mask, unsigned* __restrict__ pm) {
  int i = blockIdx.x * blockDim.x + threadIdx.x;
  if (i >= NN) return;
  unsigned m = 0;
#pragma unroll
  for (int t = 0; t < T1; ++t)
    m |= (mask[t * NN + i] == 0 ? 1u : 0u) << t;
  pm[i] = m;
}

// Observed column mean at t=16 per channel (fallback when no valid donor).
__global__ void colmean_kernel(const float* __restrict__ x_all, const int* __restrict__ mask,
                               float* __restrict__ colmean) {
  __shared__ float ssum[256][CC];
  __shared__ float scnt[256];
  int tid = threadIdx.x;
  float s[CC];
#pragma unroll
  for (int c = 0; c < CC; ++c) s[c] = 0.f;
  float cn = 0.f;
  for (int i = tid; i < NN; i += 256) {
    if (mask[16 * NN + i] == 0) {
      cn += 1.f;
      const float* row = x_all + (size_t)(16 * NN + i) * DIN;
#pragma unroll
      for (int c = 0; c < CC; ++c) s[c] += row[c];
    }
  }
#pragma unroll
  for (int c = 0; c < CC; ++c) ssum[tid][c] = s[c];
  scnt[tid] = cn;
  __syncthreads();
  for (int off = 128; off > 0; off >>= 1) {
    if (tid < off) {
#pragma unroll
      for (int c = 0; c < CC; ++c) ssum[tid][c] += ssum[tid + off][c];
      scnt[tid] += scnt[tid + off];
    }
    __syncthreads();
  }
  if (tid < CC) colmean[tid] = ssum[0][tid] / fmaxf(scnt[0], 1.f);
}

// Main: block = 512 threads = 8 waves. Lanes of each wave = 8 rows x 8 channels
// (lane = ii*8 + c). Wave r scans donor chunk [r*256, (r+1)*256) keeping a
// lex-sorted top-5 of (dist, j); partials merged via LDS.
__global__ __launch_bounds__(RR * 64) void knn_main(const float* __restrict__ x_all,
                                                    const unsigned* __restrict__ pm,
                                                    const float* __restrict__ colmean,
                                                    float* __restrict__ out) {
  __shared__ float sd[RR * 64 * KK];
  __shared__ float sv[RR * 64 * KK];
  __shared__ int sj[RR * 64 * KK];
  const int lane = threadIdx.x & 63;
  const int r = threadIdx.x >> 6;
  const int ii = lane >> 3;
  const int c = lane & 7;
  const int i = blockIdx.x * 8 + ii;
  const unsigned mi = pm[i];
  const bool pres16 = (mi >> 16) & 1u;

  // Own row values (raw loads; masked terms are zeroed via flags below).
  float xi[T1];
#pragma unroll
  for (int t = 0; t < T1; ++t)
    xi[t] = x_all[((size_t)t * NN + i) * DIN + c];

  // Lex-sorted top-5 ascending by (dist, j). Pad = (inf, INT_MAX).
  float d5[KK], v5[KK];
  int j5[KK];
#pragma unroll
  for (int k = 0; k < KK; ++k) { d5[k] = INFINITY; v5[k] = 0.f; j5[k] = 0x7FFFFFFF; }

  if (!pres16 && mi != 0u) {
    const int j0 = r * CHUNK, j1 = j0 + CHUNK;
    const float* xjbase = x_all + c;
    for (int j = j0; j < j1; ++j) {
      const unsigned mj = pm[j];
      if (!((mj >> 16) & 1u)) continue;          // donor must have value at t=16 (wave-uniform)
      const unsigned m = mi & mj;
      const int cnt = __popc(m);
      if (cnt == 0) continue;                     // nan_euclidean: no common dims -> inf
      float d2 = 0.f;
      float vj = 0.f;
      const float* xj = xjbase + (size_t)j * DIN;
#pragma unroll
      for (int t = 0; t < T1; ++t) {
        const float xjt = xj[(size_t)t * NN * DIN];
        if (t == 16) vj = xjt;
        const float diff = xi[t] - xjt;
        const float flag = (float)((m >> t) & 1u);
        d2 = fmaf(diff * diff, flag, d2);
      }
      const float dist = sqrtf(fmaxf(d2, 0.f) * (17.f / (float)cnt));
      // strict < vs current worst == top_k lower-index tie preference
      // (candidate j is the largest index seen so far)
      if (lexlt(dist, j, d5[KK - 1], j5[KK - 1])) {
        d5[KK - 1] = dist; v5[KK - 1] = vj; j5[KK - 1] = j;
#pragma unroll
        for (int k = KK - 2; k >= 0; --k) {
          if (lexlt(d5[k + 1], j5[k + 1], d5[k], j5[k])) {
            float td = d5[k]; d5[k] = d5[k + 1]; d5[k + 1] = td;
            float tv = v5[k]; v5[k] = v5[k + 1]; v5[k + 1] = tv;
            int tj = j5[k]; j5[k] = j5[k + 1]; j5[k + 1] = tj;
          }
        }
      }
    }
  }

#pragma unroll
  for (int k = 0; k < KK; ++k) {
    sd[threadIdx.x * KK + k] = d5[k];
    sv[threadIdx.x * KK + k] = v5[k];
    sj[threadIdx.x * KK + k] = j5[k];
  }
  __syncthreads();

  if (threadIdx.x < 64) {
    if (pres16) {
      out[i * CC + c] = xi[16];
    } else {
      // Merge RR partial top-5 lists: select 5 lex-smallest via threshold scan
      // (no runtime array indexing -> stays in registers).
      float pd = -INFINITY; int pj = -1;
      float sum = 0.f; int cnt = 0;
#pragma unroll
      for (int sel = 0; sel < KK; ++sel) {
        float bd = INFINITY; int bj = 0x7FFFFFFF; float bv = 0.f;
#pragma unroll
        for (int e = 0; e < RR * KK; ++e) {
          const int rr2 = e / KK, k = e % KK;
          const int src = (rr2 * 64 + lane) * KK + k;
          const float d = sd[src];
          const int j = sj[src];
          if ((d > pd || (d == pd && j > pj)) && (d < bd || (d == bd && j < bj))) {
            bd = d; bj = j; bv = sv[src];
          }
        }
        if (bd < INFINITY) { sum += bv; ++cnt; }
        pd = bd; pj = bj;
      }
      out[i * CC + c] = (cnt > 0) ? sum / (float)cnt : colmean[c];
    }
  }
}

extern "C" void kernel_launch(void* const* d_in, const int* in_sizes, int n_in,
                              void* d_out, int out_size, void* d_ws, size_t ws_size,
                              hipStream_t stream) {
  const float* x_all = (const float*)d_in[0];  // [17, 2048, 9] f32
  const int* mask = (const int*)d_in[1];       // [17, 2048] i32
  float* out = (float*)d_out;                  // [2048, 8] f32

  unsigned* pm = (unsigned*)d_ws;                       // 2048 u32
  float* colmean = (float*)((char*)d_ws + NN * 4);      // 8 f32

  prep_kernel<<<(NN + 255) / 256, 256, 0, stream>>>(mask, pm);
  colmean_kernel<<<1, 256, 0, stream>>>(x_all, mask, colmean);
  knn_main<<<NN / 8, RR * 64, 0, stream>>>(x_all, pm, colmean, out);
}

// Round 2
// 172.614 us; speedup vs baseline: 1.0129x; 1.0129x over previous
//
#include <hip/hip_runtime.h>
#include <math.h>

#define T1 17
#define NN 2048
#define DIN 9
#define CC 8
#define KK 5

// ws layout (bytes):
//   xd      : float[17][2048][8]  @ 0          (1,114,112 B) donor data, compacted+transposed
//   pm      : u32[2048]           @ XD_BYTES
//   dlist   : i32[2048]
//   pmd     : u32[2048]
//   colmean : f32[8]
//   ndon    : i32
#define XD_BYTES (T1 * NN * CC * 4)

// ---------------------------------------------------------------------------
// Prep (1 block x 1024): bitmasks, ordered compaction of valid donors
// (present at t=16), donor masks, observed column means at t=16.
__global__ __launch_bounds__(1024) void prep_kernel(
    const float* __restrict__ x_all, const int* __restrict__ mask,
    unsigned* __restrict__ pm, int* __restrict__ dlist,
    unsigned* __restrict__ pmd, float* __restrict__ colmean,
    int* __restrict__ ndon_p) {
  __shared__ unsigned long long bal[2][16];
  __shared__ int pre[33];
  __shared__ float ssum[1024][CC];  // 32KB
  const int tid = threadIdx.x;
  const int lane = tid & 63, w = tid >> 6;

  unsigned m0 = 0, m1 = 0;
#pragma unroll
  for (int t = 0; t < T1; ++t) {
    m0 |= (mask[t * NN + tid] == 0 ? 1u : 0u) << t;
    m1 |= (mask[t * NN + tid + 1024] == 0 ? 1u : 0u) << t;
  }
  pm[tid] = m0;
  pm[tid + 1024] = m1;
  const bool v0 = (m0 >> 16) & 1u, v1 = (m1 >> 16) & 1u;
  const unsigned long long b0 = __ballot(v0), b1 = __ballot(v1);
  if (lane == 0) { bal[0][w] = b0; bal[1][w] = b1; }

  // column-mean partials (rows observed at t=16)
  float s[CC];
#pragma unroll
  for (int c = 0; c < CC; ++c) s[c] = 0.f;
  if (v0) {
#pragma unroll
    for (int c = 0; c < CC; ++c) s[c] += x_all[((size_t)16 * NN + tid) * DIN + c];
  }
  if (v1) {
#pragma unroll
    for (int c = 0; c < CC; ++c) s[c] += x_all[((size_t)16 * NN + tid + 1024) * DIN + c];
  }
#pragma unroll
  for (int c = 0; c < CC; ++c) ssum[tid][c] = s[c];
  __syncthreads();

  if (tid == 0) {
    int acc = 0;
    for (int h = 0; h < 2; ++h)
      for (int q = 0; q < 16; ++q) { pre[h * 16 + q] = acc; acc += __popcll(bal[h][q]); }
    pre[32] = acc;
    *ndon_p = acc;
  }
  __syncthreads();

  const unsigned long long ltm = (1ull << lane) - 1ull;
  if (v0) { const int p = pre[w] + (int)__popcll(b0 & ltm); dlist[p] = tid; pmd[p] = m0; }
  if (v1) { const int p = pre[16 + w] + (int)__popcll(b1 & ltm); dlist[p] = tid + 1024; pmd[p] = m1; }

  for (int off = 512; off > 0; off >>= 1) {
    if (tid < off) {
#pragma unroll
      for (int c = 0; c < CC; ++c) ssum[tid][c] += ssum[tid + off][c];
    }
    __syncthreads();
  }
  if (tid < CC) colmean[tid] = ssum[0][tid] / fmaxf((float)pre[32], 1.f);
}

// ---------------------------------------------------------------------------
// Pack donor data: xd[t][dn][c] = x_all[t][dlist[dn]][c]  (32B-aligned donor rows)
__global__ void transpose_kernel(const float* __restrict__ x_all,
                                 const int* __restrict__ dlist,
                                 const int* __restrict__ ndon_p,
                                 float* __restrict__ xd) {
  const int u = blockIdx.x * 256 + threadIdx.x;
  if (u >= T1 * NN * CC) return;
  const int t = u / (NN * CC);
  const int rem = u % (NN * CC);
  const int dn = rem >> 3;
  const int c = rem & 7;
  if (dn < *ndon_p) xd[u] = x_all[((size_t)t * NN + dlist[dn]) * DIN + c];
}

// ---------------------------------------------------------------------------
// Main: one block (512 thr) per target row. Lanes own donors; all 8 channel
// distances per donor computed together; LDS materialization; per-channel
// 5-round lex-min selection (matches top_k ascending-(d,j) ties + sum order).
__global__ __launch_bounds__(512) void knn_main(
    const float* __restrict__ x_all, const float* __restrict__ xd,
    const unsigned* __restrict__ pm, const unsigned* __restrict__ pmd,
    const int* __restrict__ ndon_p, const float* __restrict__ colmean,
    float* __restrict__ out) {
  extern __shared__ float sdist[];  // [CC][NN] = 64KB
  __shared__ float4 sxi4[T1][2];
  const int tid = threadIdx.x;
  const int i = blockIdx.x;
  const unsigned mi = pm[i];

  if ((mi >> 16) & 1u) {  // present at t=16: passthrough
    if (tid < CC) out[i * CC + tid] = x_all[((size_t)16 * NN + i) * DIN + tid];
    return;
  }
  const int ndon = *ndon_p;

  if (tid < T1 * CC) ((float*)sxi4)[tid] = x_all[((size_t)(tid >> 3) * NN + i) * DIN + (tid & 7)];
  __syncthreads();

  const float4* __restrict__ xdv = (const float4*)xd;
  for (int dn = tid; dn < NN; dn += 512) {
    float d0, d1, d2c, d3, d4, d5x, d6, d7;
    if (dn < ndon) {
      const unsigned m = mi & pmd[dn];
      const int cnt = __popc(m);
      float a0 = 0.f, a1 = 0.f, a2 = 0.f, a3 = 0.f, a4 = 0.f, a5 = 0.f, a6 = 0.f, a7 = 0.f;
#pragma unroll
      for (int t = 0; t < T1; ++t) {
        const float4 qa = sxi4[t][0];
        const float4 qb = sxi4[t][1];
        const float4 da = xdv[((size_t)t * NN + dn) * 2 + 0];
        const float4 db = xdv[((size_t)t * NN + dn) * 2 + 1];
        const float fl = (float)((m >> t) & 1u);
        float e;
        e = qa.x - da.x; a0 = fmaf(e * e, fl, a0);
        e = qa.y - da.y; a1 = fmaf(e * e, fl, a1);
        e = qa.z - da.z; a2 = fmaf(e * e, fl, a2);
        e = qa.w - da.w; a3 = fmaf(e * e, fl, a3);
        e = qb.x - db.x; a4 = fmaf(e * e, fl, a4);
        e = qb.y - db.y; a5 = fmaf(e * e, fl, a5);
        e = qb.z - db.z; a6 = fmaf(e * e, fl, a6);
        e = qb.w - db.w; a7 = fmaf(e * e, fl, a7);
      }
      if (cnt > 0) {
        const float sc = 17.f / (float)cnt;
        d0 = sqrtf(fmaxf(a0, 0.f) * sc);
        d1 = sqrtf(fmaxf(a1, 0.f) * sc);
        d2c = sqrtf(fmaxf(a2, 0.f) * sc);
        d3 = sqrtf(fmaxf(a3, 0.f) * sc);
        d4 = sqrtf(fmaxf(a4, 0.f) * sc);
        d5x = sqrtf(fmaxf(a5, 0.f) * sc);
        d6 = sqrtf(fmaxf(a6, 0.f) * sc);
        d7 = sqrtf(fmaxf(a7, 0.f) * sc);
      } else {
        d0 = d1 = d2c = d3 = d4 = d5x = d6 = d7 = INFINITY;
      }
    } else {
      d0 = d1 = d2c = d3 = d4 = d5x = d6 = d7 = INFINITY;
    }
    sdist[0 * NN + dn] = d0;
    sdist[1 * NN + dn] = d1;
    sdist[2 * NN + dn] = d2c;
    sdist[3 * NN + dn] = d3;
    sdist[4 * NN + dn] = d4;
    sdist[5 * NN + dn] = d5x;
    sdist[6 * NN + dn] = d6;
    sdist[7 * NN + dn] = d7;
  }
  __syncthreads();

  // selection: wave w handles channel w
  const int lane = tid & 63, w = tid >> 6;
  const int smax = (ndon + 63) >> 6;
  float pd = -INFINITY;
  int pj = -1;
  float sum = 0.f;
  int cn = 0;
#pragma unroll
  for (int k = 0; k < KK; ++k) {
    float bd = INFINITY;
    int bj = 0x7FFFFFFF;
#pragma unroll 4
    for (int s = 0; s < smax; ++s) {
      const int dn = lane + (s << 6);
      const float d = sdist[w * NN + dn];
      const bool gt = (d > pd) || (d == pd && dn > pj);
      const bool lt = (d < bd) || (d == bd && dn < bj);
      if (gt && lt) { bd = d; bj = dn; }
    }
#pragma unroll
    for (int off = 32; off > 0; off >>= 1) {
      const float od = __shfl_xor(bd, off);
      const int oj = __shfl_xor(bj, off);
      if (od < bd || (od == bd && oj < bj)) { bd = od; bj = oj; }
    }
    if (bd < INFINITY) { sum += xd[((size_t)16 * NN + bj) * CC + w]; ++cn; }
    pd = bd;
    pj = bj;
  }
  if (lane == 0) out[i * CC + w] = (cn > 0) ? sum / (float)cn : colmean[w];
}

// ---------------------------------------------------------------------------
extern "C" void kernel_launch(void* const* d_in, const int* in_sizes, int n_in,
                              void* d_out, int out_size, void* d_ws, size_t ws_size,
                              hipStream_t stream) {
  const float* x_all = (const float*)d_in[0];  // [17, 2048, 9] f32
  const int* mask = (const int*)d_in[1];       // [17, 2048] i32
  float* out = (float*)d_out;                  // [2048, 8] f32

  char* ws = (char*)d_ws;
  float* xd = (float*)ws;
  unsigned* pm = (unsigned*)(ws + XD_BYTES);
  int* dlist = (int*)(ws + XD_BYTES + NN * 4);
  unsigned* pmd = (unsigned*)(ws + XD_BYTES + NN * 8);
  float* colmean = (float*)(ws + XD_BYTES + NN * 12);
  int* ndon_p = (int*)(ws + XD_BYTES + NN * 12 + CC * 4);

  prep_kernel<<<1, 1024, 0, stream>>>(x_all, mask, pm, dlist, pmd, colmean, ndon_p);
  transpose_kernel<<<(T1 * NN * CC + 255) / 256, 256, 0, stream>>>(x_all, dlist, ndon_p, xd);
  knn_main<<<NN, 512, CC * NN * 4, stream>>>(x_all, xd, pm, pmd, ndon_p, colmean, out);
}